// Round 2
// baseline (232.104 us; speedup 1.0000x reference)
//
#include <hip/hip_runtime.h>
#include <hip/hip_bf16.h>

// Hmoe: gate = sigmoid(x @ w + b); tree-product over 6 levels -> P (32768 x 64);
// out = P @ responses.
// Kernel 0a: convert+transpose responses -> RT bf16 [2048][64] (ws)
// Kernel 0b: convert+transpose w -> wTh/wTl bf16 [64][2048] hi/lo split (ws)
// Kernel 1: gate GEMM, A-frags straight from global f32 (converted in regs),
//           B-frags straight from global bf16 (L2-resident). No barriers in
//           K-loop. Epilogue: sigmoid -> LDS -> leaf-prob tree -> P bf16.
// Kernel 2: out = P @ RT via bf16 MFMA, f32 out.

typedef short bf16x8 __attribute__((ext_vector_type(8)));
typedef float f32x4  __attribute__((ext_vector_type(4)));

#define BS    32768
#define DIMX  2048
#define NODES 63
#define NL    64
#define DIMY  2048

__device__ __forceinline__ unsigned short f2bf(float f) {
    union { float f; unsigned int u; } v; v.f = f;
    unsigned int r = v.u + 0x7FFFu + ((v.u >> 16) & 1u);   // round-to-nearest-even
    return (unsigned short)(r >> 16);
}
__device__ __forceinline__ float bf2f(unsigned short h) {
    union { float f; unsigned int u; } v; v.u = ((unsigned int)h) << 16;
    return v.f;
}

// ---------------- kernel 0a: responses f32 [64][2048] -> RT bf16 [2048][64] ---
__global__ __launch_bounds__(256) void rt_conv(const float* __restrict__ R,
                                               unsigned short* __restrict__ RT) {
    int f = blockIdx.x * 256 + threadIdx.x;     // 131072 total
    int n = f >> 6;
    int k = f & 63;
    RT[f] = f2bf(R[k * DIMY + n]);              // writes coalesced; reads strided (tiny, L2)
}

// ---------------- kernel 0b: w f32 [2048][63] -> wT hi/lo bf16 [64][2048] -----
__global__ __launch_bounds__(256) void wt_conv(const float* __restrict__ w,
                                               unsigned short* __restrict__ wTh,
                                               unsigned short* __restrict__ wTl) {
    int f = blockIdx.x * 256 + threadIdx.x;     // 64*2048 total
    int n = f >> 11;                            // node 0..63
    int k = f & 2047;
    float v = (n < NODES) ? w[(size_t)k * NODES + n] : 0.0f;
    unsigned short h = f2bf(v);
    wTh[f] = h;
    wTl[f] = f2bf(v - bf2f(h));
}

// ---------------- kernel 1: gates + tree -> P --------------------------------
#define BM 128      // rows per block: 4 waves x 2 row-frags x 16

__device__ __forceinline__ bf16x8 pack8(float4 a, float4 b) {
    bf16x8 r;
    r[0] = (short)f2bf(a.x); r[1] = (short)f2bf(a.y);
    r[2] = (short)f2bf(a.z); r[3] = (short)f2bf(a.w);
    r[4] = (short)f2bf(b.x); r[5] = (short)f2bf(b.y);
    r[6] = (short)f2bf(b.z); r[7] = (short)f2bf(b.w);
    return r;
}

__global__ __launch_bounds__(256) void gate_kernel(const float* __restrict__ x,
                                                   const unsigned short* __restrict__ wTh,
                                                   const unsigned short* __restrict__ wTl,
                                                   const float* __restrict__ bias,
                                                   unsigned short* __restrict__ P) {
    __shared__ float gl[BM][NL + 1];            // gates, +1 pad (33.3 KB)

    const int t    = threadIdx.x;
    const int lane = t & 63;
    const int wv   = t >> 6;        // 4 waves
    const int lr   = lane & 15;
    const int lg   = lane >> 4;
    const int m0   = blockIdx.x * BM;
    const int r0   = wv * 32;       // each wave owns 32 rows (2 row-frags)

    f32x4 acc[2][4];
    #pragma unroll
    for (int rm = 0; rm < 2; ++rm)
        #pragma unroll
        for (int cf = 0; cf < 4; ++cf) acc[rm][cf] = (f32x4){0.f, 0.f, 0.f, 0.f};

    const float* xp0 = x + (size_t)(m0 + r0 + lr) * DIMX + lg * 8;
    const float* xp1 = xp0 + (size_t)16 * DIMX;

    #pragma unroll 4
    for (int kk = 0; kk < DIMX; kk += 32) {
        float4 v0 = *(const float4*)(xp0 + kk);
        float4 v1 = *(const float4*)(xp0 + kk + 4);
        float4 u0 = *(const float4*)(xp1 + kk);
        float4 u1 = *(const float4*)(xp1 + kk + 4);
        bf16x8 a0 = pack8(v0, v1);
        bf16x8 a1 = pack8(u0, u1);
        const int ko = kk + lg * 8;
        #pragma unroll
        for (int cf = 0; cf < 4; ++cf) {
            const size_t nb = (size_t)(cf * 16 + lr) * DIMX + ko;
            bf16x8 bh = *(const bf16x8*)(wTh + nb);
            bf16x8 bo = *(const bf16x8*)(wTl + nb);
            acc[0][cf] = __builtin_amdgcn_mfma_f32_16x16x32_bf16(a0, bh, acc[0][cf], 0, 0, 0);
            acc[1][cf] = __builtin_amdgcn_mfma_f32_16x16x32_bf16(a1, bh, acc[1][cf], 0, 0, 0);
            acc[0][cf] = __builtin_amdgcn_mfma_f32_16x16x32_bf16(a0, bo, acc[0][cf], 0, 0, 0);
            acc[1][cf] = __builtin_amdgcn_mfma_f32_16x16x32_bf16(a1, bo, acc[1][cf], 0, 0, 0);
        }
    }

    // bias + sigmoid -> gates in LDS.  D-frag: row=(lane>>4)*4+reg, col=lane&15.
    #pragma unroll
    for (int rm = 0; rm < 2; ++rm) {
        #pragma unroll
        for (int cf = 0; cf < 4; ++cf) {
            const int col = cf * 16 + lr;
            const float bb = bias[col < NODES ? col : 0];   // col 63 unused downstream
            #pragma unroll
            for (int i = 0; i < 4; ++i) {
                int row = r0 + rm * 16 + lg * 4 + i;
                float s = acc[rm][cf][i] + bb;
                gl[row][col] = 1.0f / (1.0f + __expf(-s));
            }
        }
    }
    __syncthreads();

    // leaf probabilities: 2 threads per row; b5 = t&1 is the *32 bit.
    {
        const int rr = t >> 1;          // 0..127
        const int b5 = t & 1;
        const float* g = gl[rr];
        float a2[2], a4[4], a8[8], a16[16];
        float g0 = g[0];
        a2[0] = g0; a2[1] = 1.f - g0;
        #pragma unroll
        for (int m = 0; m < 4; ++m) {
            float gg = g[1 + (m & 1)];
            a4[m] = a2[m & 1] * ((m & 2) ? (1.f - gg) : gg);
        }
        #pragma unroll
        for (int m = 0; m < 8; ++m) {
            float gg = g[3 + (m & 3)];
            a8[m] = a4[m & 3] * ((m & 4) ? (1.f - gg) : gg);
        }
        #pragma unroll
        for (int m = 0; m < 16; ++m) {
            float gg = g[7 + (m & 7)];
            a16[m] = a8[m & 7] * ((m & 8) ? (1.f - gg) : gg);
        }
        unsigned short o[32];
        #pragma unroll
        for (int m = 0; m < 16; ++m) {
            float g5 = g[15 + m];
            #pragma unroll
            for (int b4 = 0; b4 < 2; ++b4) {
                float p = a16[m] * (b4 ? (1.f - g5) : g5);
                float g6 = g[31 + m + 16 * b4];
                p *= b5 ? (1.f - g6) : g6;
                o[m + 16 * b4] = f2bf(p);
            }
        }
        unsigned short* dst = &P[(size_t)(m0 + rr) * NL + b5 * 32];
        #pragma unroll
        for (int q = 0; q < 4; ++q) {
            uint4 qq;
            qq.x = (unsigned)o[q * 8 + 0] | ((unsigned)o[q * 8 + 1] << 16);
            qq.y = (unsigned)o[q * 8 + 2] | ((unsigned)o[q * 8 + 3] << 16);
            qq.z = (unsigned)o[q * 8 + 4] | ((unsigned)o[q * 8 + 5] << 16);
            qq.w = (unsigned)o[q * 8 + 6] | ((unsigned)o[q * 8 + 7] << 16);
            *(uint4*)(dst + q * 8) = qq;
        }
    }
}

// ---------------- kernel 2: out = P @ RT^T (P: MxK=64, RT: [n][k]) -----------
#define OBM  128
#define OBN  128
#define OLD  72

__global__ __launch_bounds__(256) void out_kernel(const unsigned short* __restrict__ P,
                                                  const unsigned short* __restrict__ RT,
                                                  float* __restrict__ out) {
    __shared__ __align__(16) unsigned short ps[OBM][OLD];
    __shared__ __align__(16) unsigned short rs[OBN][OLD];
    const int t  = threadIdx.x;
    const int n0 = blockIdx.x * OBN;
    const int m0 = blockIdx.y * OBM;

    // stage P tile (128x64) and RT tile (128x64): 1024 16B chunks each
    #pragma unroll
    for (int p = 0; p < 4; ++p) {
        int c   = p * 256 + t;
        int row = c >> 3;
        int c8  = c & 7;
        *(uint4*)&ps[row][c8 * 8] = *(const uint4*)&P [(size_t)(m0 + row) * NL + c8 * 8];
        *(uint4*)&rs[row][c8 * 8] = *(const uint4*)&RT[(size_t)(n0 + row) * NL + c8 * 8];
    }
    __syncthreads();

    const int lane = t & 63;
    const int wv   = t >> 6;
    const int wm   = (wv >> 1) * 64;   // wave tile 64x64
    const int wn   = (wv & 1) * 64;
    const int lr   = lane & 15;
    const int lg   = lane >> 4;

    f32x4 acc[4][4];
    #pragma unroll
    for (int rf = 0; rf < 4; ++rf)
        #pragma unroll
        for (int cf = 0; cf < 4; ++cf) acc[rf][cf] = (f32x4){0.f, 0.f, 0.f, 0.f};

    #pragma unroll
    for (int kk = 0; kk < NL; kk += 32) {
        bf16x8 a[4], bb[4];
        #pragma unroll
        for (int rf = 0; rf < 4; ++rf)
            a[rf] = *(const bf16x8*)&ps[wm + rf * 16 + lr][kk + lg * 8];
        #pragma unroll
        for (int cf = 0; cf < 4; ++cf)
            bb[cf] = *(const bf16x8*)&rs[wn + cf * 16 + lr][kk + lg * 8];
        #pragma unroll
        for (int rf = 0; rf < 4; ++rf)
            #pragma unroll
            for (int cf = 0; cf < 4; ++cf)
                acc[rf][cf] = __builtin_amdgcn_mfma_f32_16x16x32_bf16(a[rf], bb[cf],
                                                                      acc[rf][cf], 0, 0, 0);
    }

    #pragma unroll
    for (int rf = 0; rf < 4; ++rf) {
        #pragma unroll
        for (int cf = 0; cf < 4; ++cf) {
            #pragma unroll
            for (int i = 0; i < 4; ++i) {
                int row = m0 + wm + rf * 16 + lg * 4 + i;
                int col = n0 + wn + cf * 16 + lr;
                out[(size_t)row * DIMY + col] = acc[rf][cf][i];
            }
        }
    }
}

extern "C" void kernel_launch(void* const* d_in, const int* in_sizes, int n_in,
                              void* d_out, int out_size, void* d_ws, size_t ws_size,
                              hipStream_t stream) {
    const float* x = (const float*)d_in[0];
    const float* w = (const float*)d_in[1];
    const float* b = (const float*)d_in[2];
    const float* R = (const float*)d_in[3];
    float* out = (float*)d_out;

    char* ws = (char*)d_ws;
    unsigned short* P   = (unsigned short*)ws;                                  // 4 MB
    unsigned short* RT  = (unsigned short*)(ws + (size_t)BS * NL * 2);          // 256 KB
    unsigned short* wTh = (unsigned short*)(ws + (size_t)BS * NL * 2 + 262144); // 256 KB
    unsigned short* wTl = (unsigned short*)(ws + (size_t)BS * NL * 2 + 524288); // 256 KB

    rt_conv<<<dim3((NL * DIMY) / 256), 256, 0, stream>>>(R, RT);
    wt_conv<<<dim3((NL * DIMX) / 256), 256, 0, stream>>>(w, wTh, wTl);
    gate_kernel<<<dim3(BS / BM), 256, 0, stream>>>(x, wTh, wTl, b, P);
    out_kernel<<<dim3(DIMY / OBN, BS / OBM), 256, 0, stream>>>(P, RT, out);
}